// Round 13
// baseline (233.029 us; speedup 1.0000x reference)
//
#include <hip/hip_runtime.h>
#include <hip/hip_bf16.h>
#include <math.h>

// Problem constants
#define B_     4
#define T_     4096
#define H_     8
#define LD_    128
#define FFN_   512
#define D_     1024
#define TED_   2048
#define TWO_D_ 2048
#define NTOK_  (B_ * T_)      // 16384
#define LN_EPS_ 1e-5f

// ws layout (bytes)
#define WS_EMB_OFF   0                         // 32 KB   (B x 2D fp32)
#define WS_IMG1_OFF  (64 * 1024)               // 1 MB  bf16 fragment-ordered W1^T
#define WS_IMG2_OFF  ((64 << 10) + (1 << 20))  // 1 MB  bf16 fragment-ordered W2^T
#define WS_IMGO_OFF  ((64 << 10) + (2 << 20))  // 2 MB  bf16 [n=1024][k=1024]
#define WS_Y_OFF     (8 << 20)                 // 32 MB bf16 y (raw, pre-LN)

typedef short bf16x8 __attribute__((ext_vector_type(8)));
typedef float f32x4  __attribute__((ext_vector_type(4)));
typedef float f32x16 __attribute__((ext_vector_type(16)));
typedef unsigned int u32x4 __attribute__((ext_vector_type(4)));

// fast SiLU: v * rcp(1 + exp(-v))
__device__ __forceinline__ float siluf(float v) {
  return v * __builtin_amdgcn_rcpf(1.0f + __expf(-v));
}
// fast exact-GELU via Abramowitz-Stegun 7.1.26 erf (|eps| <= 1.5e-7)
__device__ __forceinline__ float geluf(float v) {
  const float s  = v * 0.70710678118654752440f;
  const float ax = fabsf(s);
  const float t  = __builtin_amdgcn_rcpf(fmaf(0.3275911f, ax, 1.0f));
  const float e  = __expf(-ax * ax);
  float p = fmaf(1.061405429f, t, -1.453152027f);
  p = fmaf(p, t, 1.421413741f);
  p = fmaf(p, t, -0.284496736f);
  p = fmaf(p, t, 0.254829592f);
  p = p * t;
  const float erf_ax = fmaf(-p, e, 1.0f);
  const float erf_s  = copysignf(erf_ax, s);
  return 0.5f * v * (1.0f + erf_s);
}
// HW packed f32x2 -> bf16x2 (RNE), single VALU op (T12 recipe; no builtin).
__device__ __forceinline__ unsigned int pack2(float a, float b) {
  unsigned int r;
  asm("v_cvt_pk_bf16_f32 %0, %1, %2" : "=v"(r) : "v"(a), "v"(b));
  return r;
}
__device__ __forceinline__ void unpack8(uint4 u, float* v) {
  v[0] = __uint_as_float(u.x << 16); v[1] = __uint_as_float(u.x & 0xffff0000u);
  v[2] = __uint_as_float(u.y << 16); v[3] = __uint_as_float(u.y & 0xffff0000u);
  v[4] = __uint_as_float(u.z << 16); v[5] = __uint_as_float(u.z & 0xffff0000u);
  v[6] = __uint_as_float(u.w << 16); v[7] = __uint_as_float(u.w & 0xffff0000u);
}

// async global->LDS, 16B/lane; LDS dest is wave-uniform base + lane*16.
__device__ __forceinline__ void gload_lds16(const void* g, void* l) {
#pragma clang diagnostic push
#pragma clang diagnostic ignored "-Waddress-space-conversion"
  __builtin_amdgcn_global_load_lds(
      (const __attribute__((address_space(1))) unsigned int*)g,
      (__attribute__((address_space(3))) unsigned int*)l, 16, 0, 0);
#pragma clang diagnostic pop
}

// ---------------------------------------------------------------------------
// kinit (r9 version): fused weight-prep + emb projection.
//  t <  32 : img1 frag-ordered for 32x32x16 (k1): (c*8+kb)*512 + l*8
//  t <  64 : img2 frag-ordered for 32x32x16 (k1): (c*8+kb2*4+nt)*512 + l*8
//  t < 128 : imgO[n=1024][k=1024] = out_W[k][n]
//  t < 256 : emb_out = silu(emb) @ emb_W + emb_b (k-split + atomics)
// ---------------------------------------------------------------------------
__global__ __launch_bounds__(256) void kinit(
    const float* __restrict__ W1, const float* __restrict__ W2,
    const float* __restrict__ out_W,
    const float* __restrict__ emb, const float* __restrict__ emb_W,
    const float* __restrict__ emb_b,
    unsigned short* __restrict__ img1, unsigned short* __restrict__ img2,
    unsigned short* __restrict__ imgO, float* __restrict__ emb_out) {
  const int t = blockIdx.x;
  const int tid = threadIdx.x;
  if (t < 64) {
    const bool is1 = (t < 32);
    const int h = (t & 31) >> 2, q = t & 3;
    const int l = tid & 63, fg = tid >> 6;
    const int l31 = l & 31, hi8 = (l >> 5) * 8;
    #pragma unroll
    for (int i = 0; i < 8; ++i) {
      const int fid = fg * 8 + i;           // 0..31 within quarter
      float val[8];
      size_t dsto;
      if (is1) {
        const int c = q * 4 + (fid >> 3), kb = fid & 7;
        const float* sp = W1 + (size_t)h * 65536 +
                          (size_t)(kb * 16 + hi8) * 512 + c * 32 + l31;
        #pragma unroll
        for (int j = 0; j < 8; ++j) val[j] = sp[(size_t)j * 512];
        dsto = (size_t)h * 65536 + (size_t)(c * 8 + kb) * 512 + l * 8;
      } else {
        const int c = q * 4 + (fid >> 3), kb2 = (fid >> 2) & 1, nt = fid & 3;
        const float* sp = W2 + (size_t)h * 65536 +
                          (size_t)(c * 32 + kb2 * 16 + hi8) * 128 + nt * 32 + l31;
        #pragma unroll
        for (int j = 0; j < 8; ++j) val[j] = sp[(size_t)j * 128];
        dsto = (size_t)h * 65536 + (size_t)(c * 8 + kb2 * 4 + nt) * 512 + l * 8;
      }
      unsigned int p[4];
      #pragma unroll
      for (int qq = 0; qq < 4; ++qq) p[qq] = pack2(val[2 * qq], val[2 * qq + 1]);
      *reinterpret_cast<uint4*>((is1 ? img1 : img2) + dsto) =
          make_uint4(p[0], p[1], p[2], p[3]);
    }
    return;
  }
  if (t < 128) {
    __shared__ float ls[128][129];
    const int tt = t - 64, tr = tt >> 3, tc = tt & 7;
    const float* src = out_W + (size_t)tr * 128 * 1024 + tc * 128;
    unsigned short* dst = imgO + (size_t)tc * 128 * 1024 + tr * 128;
    for (int i = tid; i < 128 * 32; i += 256) {
      const int r = i >> 5, c4 = (i & 31) << 2;
      const float4 v = *reinterpret_cast<const float4*>(src + (size_t)r * 1024 + c4);
      ls[r][c4] = v.x; ls[r][c4 + 1] = v.y; ls[r][c4 + 2] = v.z; ls[r][c4 + 3] = v.w;
    }
    __syncthreads();
    for (int u = tid; u < 2048; u += 256) {
      const int nn = u >> 4, kb = (u & 15) << 3;
      unsigned int p[4];
      #pragma unroll
      for (int qq = 0; qq < 4; ++qq)
        p[qq] = pack2(ls[kb + 2 * qq][nn], ls[kb + 2 * qq + 1][nn]);
      *reinterpret_cast<uint4*>(dst + (size_t)nn * 1024 + kb) =
          make_uint4(p[0], p[1], p[2], p[3]);
    }
    return;
  }
  {
    __shared__ float se[B_][128];
    const int bid = t - 128;
    const int j   = (bid & 7) * 256 + tid;
    const int k0  = (bid >> 3) * 128;
    for (int i = tid; i < B_ * 128; i += 256) {
      const int b = i >> 7, k = i & 127;
      se[b][k] = siluf(emb[b * TED_ + k0 + k]);
    }
    __syncthreads();
    float a0 = 0.f, a1 = 0.f, a2 = 0.f, a3 = 0.f;
    const float* Wp = emb_W + (size_t)k0 * TWO_D_ + j;
    for (int k = 0; k < 128; ++k) {
      const float w = Wp[(size_t)k * TWO_D_];
      a0 += se[0][k] * w; a1 += se[1][k] * w;
      a2 += se[2][k] * w; a3 += se[3][k] * w;
    }
    if ((bid >> 3) == 0) {
      const float bb = emb_b[j];
      a0 += bb; a1 += bb; a2 += bb; a3 += bb;
    }
    atomicAdd(&emb_out[0 * TWO_D_ + j], a0);
    atomicAdd(&emb_out[1 * TWO_D_ + j], a1);
    atomicAdd(&emb_out[2 * TWO_D_ + j], a2);
    atomicAdd(&emb_out[3 * TWO_D_ + j], a3);
  }
}

// ---------------------------------------------------------------------------
// k1 (r9 version, best-known: 93 us, 0 bank conflicts): per-head MLP,
// 4 waves x 32 tokens, 2-phase dbuf LDS weight staging, cvt_pk, setprio.
// ---------------------------------------------------------------------------
__global__ __launch_bounds__(256, 3) void k1_mfma(
    const float* __restrict__ x,
    const unsigned short* __restrict__ img1,
    const unsigned short* __restrict__ img2,
    const float* __restrict__ b1, const float* __restrict__ b2,
    unsigned short* __restrict__ y) {
  __shared__ unsigned short wbuf[2][16 * 512];  // 2 x 16 KB
  const int h = blockIdx.y;
  const int tid = threadIdx.x, w = tid >> 6, l = tid & 63;
  const int t0 = blockIdx.x * 128 + w * 32;
  const int l31 = l & 31, hi = l >> 5;

  const unsigned short* s1 = img1 + ((size_t)h << 16);
  const unsigned short* s2 = img2 + ((size_t)h << 16);

  auto stage = [&](unsigned short* buf, int c) {
    #pragma unroll
    for (int i = 0; i < 4; ++i) {
      const int slot = w * 4 + i;                     // wave-uniform
      const unsigned short* src = (slot < 8)
          ? (s1 + (size_t)(c * 8 + slot) * 512 + l * 8)
          : (s2 + (size_t)(c * 8 + (slot - 8)) * 512 + l * 8);
      gload_lds16(src, buf + slot * 512);
    }
  };

  bf16x8 xf[8];
  {
    const float* xr = x + (size_t)(t0 + l31) * D_ + h * LD_ + hi * 8;
    #pragma unroll
    for (int kb = 0; kb < 8; ++kb) {
      const float4 a = *reinterpret_cast<const float4*>(xr + kb * 16);
      const float4 b = *reinterpret_cast<const float4*>(xr + kb * 16 + 4);
      u32x4 u;
      u[0] = pack2(a.x, a.y); u[1] = pack2(a.z, a.w);
      u[2] = pack2(b.x, b.y); u[3] = pack2(b.z, b.w);
      xf[kb] = __builtin_bit_cast(bf16x8, u);
    }
  }

  f32x16 acc2[4];
  #pragma unroll
  for (int nt = 0; nt < 4; ++nt)
    #pragma unroll
    for (int r = 0; r < 16; ++r) acc2[nt][r] = 0.f;

  auto compute = [&](const unsigned short* buf, int c) {
    f32x16 acc1;
    #pragma unroll
    for (int r = 0; r < 16; ++r) acc1[r] = 0.f;
    __builtin_amdgcn_s_setprio(1);
    #pragma unroll
    for (int kb = 0; kb < 8; ++kb) {
      const bf16x8 a = *reinterpret_cast<const bf16x8*>(buf + kb * 512 + l * 8);
      acc1 = __builtin_amdgcn_mfma_f32_32x32x16_bf16(a, xf[kb], acc1, 0, 0, 0);
    }
    __builtin_amdgcn_s_setprio(0);
    float g[16];
    #pragma unroll
    for (int q = 0; q < 4; ++q) {
      const float4 bq = *reinterpret_cast<const float4*>(
          b1 + h * FFN_ + c * 32 + q * 8 + hi * 4);
      g[q*4+0] = geluf(acc1[q*4+0] + bq.x);
      g[q*4+1] = geluf(acc1[q*4+1] + bq.y);
      g[q*4+2] = geluf(acc1[q*4+2] + bq.z);
      g[q*4+3] = geluf(acc1[q*4+3] + bq.w);
    }
    unsigned int P[4][2];
    #pragma unroll
    for (int q = 0; q < 4; ++q) {
      P[q][0] = pack2(g[q*4+0], g[q*4+1]);
      P[q][1] = pack2(g[q*4+2], g[q*4+3]);
    }
    unsigned int A2[2][4];
    #pragma unroll
    for (int half = 0; half < 2; ++half) {
      const int qe = half * 2, qo = half * 2 + 1;
      #pragma unroll
      for (int s = 0; s < 2; ++s) {
        const unsigned int offer = hi ? P[qe][s] : P[qo][s];
        const unsigned int recv =
            (unsigned int)__shfl_xor((int)offer, 32);
        A2[half][s]     = hi ? recv : P[qe][s];
        A2[half][s + 2] = hi ? P[qo][s] : recv;
      }
    }
    __builtin_amdgcn_s_setprio(1);
    #pragma unroll
    for (int kb2 = 0; kb2 < 2; ++kb2) {
      u32x4 t;
      t[0] = A2[kb2][0]; t[1] = A2[kb2][1];
      t[2] = A2[kb2][2]; t[3] = A2[kb2][3];
      const bf16x8 a2 = __builtin_bit_cast(bf16x8, t);
      #pragma unroll
      for (int nt = 0; nt < 4; ++nt) {
        const bf16x8 b2f = *reinterpret_cast<const bf16x8*>(
            buf + (8 + kb2 * 4 + nt) * 512 + l * 8);
        acc2[nt] = __builtin_amdgcn_mfma_f32_32x32x16_bf16(a2, b2f, acc2[nt], 0, 0, 0);
      }
    }
    __builtin_amdgcn_s_setprio(0);
  };

  stage(wbuf[0], 0);
  __syncthreads();
  #pragma unroll 1
  for (int c = 0; c < 16; c += 2) {
    if (c + 1 < 16) stage(wbuf[1], c + 1);
    compute(wbuf[0], c);
    __syncthreads();
    if (c + 2 < 16) stage(wbuf[0], c + 2);
    compute(wbuf[1], c + 1);
    __syncthreads();
  }

  #pragma unroll
  for (int nt = 0; nt < 4; ++nt) {
    const int d = nt * 32 + l31;
    const float bb = b2[h * LD_ + d];
    #pragma unroll
    for (int rp = 0; rp < 8; ++rp) {
      const int r0 = 2 * rp, r1 = 2 * rp + 1;
      const unsigned int pk = pack2(acc2[nt][r0] + bb, acc2[nt][r1] + bb);
      const int tA = t0 + (r0 & 3) + 8 * (r0 >> 2) + 4 * hi;
      const int tB = tA + 1;
      y[(size_t)tA * D_ + h * LD_ + d] = (unsigned short)(pk & 0xffffu);
      y[(size_t)tB * D_ + h * LD_ + d] = (unsigned short)(pk >> 16);
    }
  }
}

// ---------------------------------------------------------------------------
// k3f: FUSED LN+modulate+SiLU + GEMM + residual.
//   out = x + silu( (LN(y)*lw+lb)*(1+sc) + sh ) @ out_W + out_b
// 256x256 tile, BK=64, 8 waves, 2-phase staging, T2 swizzle (r11 core).
// Block rows are one batch b (4096-row batches; 256-row blocks) so sc/sh are
// block-constant per column. Prologue (overlapped with stage(0)):
//   - per-row mu*rstd, rstd from raw y (rows read once, coalesced)
//   - per-col lwsc = lw*(1+sc), lbs = lb*(1+sc)+sh  (8 KB LDS)
// A-fragments are transformed in-register before MFMA:
//   t = v*(rstd*lwsc) + (lbs - murs*lwsc); a = silu(t)   [bf16 via cvt_pk]
// Same bf16 rounding point as the old k2 -> identical numerics.
// ---------------------------------------------------------------------------
__global__ __launch_bounds__(512, 1) void k3f(
    const unsigned short* __restrict__ yb,
    const unsigned short* __restrict__ imgO,
    const float* __restrict__ out_b, const float* __restrict__ x,
    const float* __restrict__ ln_w, const float* __restrict__ ln_b,
    const float* __restrict__ emb_out, float* __restrict__ out) {
  __shared__ unsigned short As[2][256 * 64];   // 2 x 32 KB (swizzled content)
  __shared__ unsigned short Bs[2][256 * 64];   // 2 x 32 KB
  __shared__ float murs_s[256];                // mu*rstd per row
  __shared__ float rstd_s[256];                // rstd per row
  __shared__ float lwsc_s[1024];               // lw*(1+sc) per col
  __shared__ float lbs_s[1024];                // lb*(1+sc)+sh per col
  const int bid = blockIdx.x;
  const int swz = (bid & 7) * 32 + (bid >> 3);   // XCD-bijective (256 % 8 == 0)
  const int m0 = (swz >> 2) * 256;
  const int n0 = (swz & 3) * 256;
  const int b  = m0 >> 12;                       // batch (block-constant)
  const int tid = threadIdx.x, w = tid >> 6, l = tid & 63;
  const int lr = l & 15, lg = l >> 4;
  const int wr = (w >> 2) * 128;
  const int wc = (w & 3) * 64;

  f32x4 acc[8][4];
  #pragma unroll
  for (int mf = 0; mf < 8; ++mf)
    #pragma unroll
    for (int nf = 0; nf < 4; ++nf)
      acc[mf][nf] = (f32x4){0.f, 0.f, 0.f, 0.f};

  const int grl  = l >> 3;
  const int gcol = (((l & 7) ^ ((l >> 3) & 7)) * 8);

  auto stage = [&](int kt, int bb) {
    #pragma unroll
    for (int j = 0; j < 4; ++j) {
      const int slab = j * 8 + w;
      const int row = slab * 8 + grl;
      gload_lds16(yb   + (size_t)(m0 + row) * D_ + kt * 64 + gcol,
                  &As[bb][slab * 512]);
      gload_lds16(imgO + (size_t)(n0 + row) * D_ + kt * 64 + gcol,
                  &Bs[bb][slab * 512]);
    }
  };

  // issue first stage, then do the prologue under its latency
  stage(0, 0);

  // ---- prologue A: per-row LN stats (wave w -> rows w*32 .. w*32+31)
  {
    #pragma unroll 1
    for (int i = 0; i < 32; ++i) {
      const int row = w * 32 + i;
      const unsigned short* rp = yb + (size_t)(m0 + row) * D_ + l * 16;
      const uint4 u0 = *reinterpret_cast<const uint4*>(rp);
      const uint4 u1 = *reinterpret_cast<const uint4*>(rp + 8);
      float v[16];
      unpack8(u0, v); unpack8(u1, v + 8);
      float s = 0.f, s2 = 0.f;
      #pragma unroll
      for (int j = 0; j < 16; ++j) { s += v[j]; s2 += v[j] * v[j]; }
      #pragma unroll
      for (int off = 1; off < 64; off <<= 1) {
        s  += __shfl_xor(s, off);
        s2 += __shfl_xor(s2, off);
      }
      if (l == 0) {
        const float mu   = s * (1.0f / D_);
        const float rstd = rsqrtf(s2 * (1.0f / D_) - mu * mu + LN_EPS_);
        murs_s[row] = mu * rstd;
        rstd_s[row] = rstd;
      }
    }
  }
  // ---- prologue B: per-col modulate constants (2 cols per thread)
  {
    #pragma unroll
    for (int e = 0; e < 2; ++e) {
      const int c = tid * 2 + e;
      const float sc = emb_out[(size_t)b * TWO_D_ + c];
      const float sh = emb_out[(size_t)b * TWO_D_ + D_ + c];
      const float os = 1.0f + sc;
      lwsc_s[c] = ln_w[c] * os;
      lbs_s[c]  = fmaf(ln_b[c], os, sh);
    }
  }
  __syncthreads();   // prologue LDS ready AND stage(0) drained (vmcnt in barrier)

  // per-lane row constants (rows fixed across K-tiles)
  float murs8[8], rstd8[8];
  #pragma unroll
  for (int mf = 0; mf < 8; ++mf) {
    const int row = wr + mf * 16 + lr;
    murs8[mf] = murs_s[row];
    rstd8[mf] = rstd_s[row];
  }

  auto compute = [&](int bb, int kt) {
    #pragma unroll
    for (int ks = 0; ks < 2; ++ks) {
      const int colu = ks * 4 + lg;          // k-unit 0..7 within tile
      // per-col constants for this unit's 8 columns (broadcast reads)
      const float* lwp = &lwsc_s[kt * 64 + colu * 8];
      const float* lbp = &lbs_s[kt * 64 + colu * 8];
      float lwv[8], lbv[8];
      {
        const float4 a0 = *reinterpret_cast<const float4*>(lwp);
        const float4 a1 = *reinterpret_cast<const float4*>(lwp + 4);
        const float4 c0 = *reinterpret_cast<const float4*>(lbp);
        const float4 c1 = *reinterpret_cast<const float4*>(lbp + 4);
        lwv[0]=a0.x; lwv[1]=a0.y; lwv[2]=a0.z; lwv[3]=a0.w;
        lwv[4]=a1.x; lwv[5]=a1.y; lwv[6]=a1.z; lwv[7]=a1.w;
        lbv[0]=c0.x; lbv[1]=c0.y; lbv[2]=c0.z; lbv[3]=c0.w;
        lbv[4]=c1.x; lbv[5]=c1.y; lbv[6]=c1.z; lbv[7]=c1.w;
      }
      bf16x8 af[8], bf[4];
      #pragma unroll
      for (int mf = 0; mf < 8; ++mf) {
        const int row = wr + mf * 16 + lr;
        const int u = colu ^ (row & 7);
        const bf16x8 raw = *reinterpret_cast<const bf16x8*>(
            &As[bb][row * 64 + u * 8]);
        float vv[8];
        unpack8(__builtin_bit_cast(uint4, raw), vv);
        unsigned int pk[4];
        #pragma unroll
        for (int j2 = 0; j2 < 4; ++j2) {
          float o2[2];
          #pragma unroll
          for (int e = 0; e < 2; ++e) {
            const int j = j2 * 2 + e;
            const float tl = fmaf(vv[j], rstd8[mf] * lwv[j],
                                  fmaf(-murs8[mf], lwv[j], lbv[j]));
            o2[e] = siluf(tl);
          }
          pk[j2] = pack2(o2[0], o2[1]);
        }
        af[mf] = __builtin_bit_cast(bf16x8,
                                    make_uint4(pk[0], pk[1], pk[2], pk[3]));
      }
      #pragma unroll
      for (int nf = 0; nf < 4; ++nf) {
        const int row = wc + nf * 16 + lr;
        const int u = colu ^ (row & 7);
        bf[nf] = *reinterpret_cast<const bf16x8*>(&Bs[bb][row * 64 + u * 8]);
      }
      __builtin_amdgcn_s_setprio(1);
      #pragma unroll
      for (int mf = 0; mf < 8; ++mf)
        #pragma unroll
        for (int nf = 0; nf < 4; ++nf)
          acc[mf][nf] = __builtin_amdgcn_mfma_f32_16x16x32_bf16(
              af[mf], bf[nf], acc[mf][nf], 0, 0, 0);
      __builtin_amdgcn_s_setprio(0);
    }
  };

  #pragma unroll 1
  for (int kt = 0; kt < 16; ++kt) {
    const int cur = kt & 1;
    if (kt + 1 < 16) stage(kt + 1, cur ^ 1);  // hides under 64 MFMA + VALU
    compute(cur, kt);
    __syncthreads();
  }

  #pragma unroll
  for (int mf = 0; mf < 8; ++mf) {
    #pragma unroll
    for (int nf = 0; nf < 4; ++nf) {
      const int n = n0 + wc + nf * 16 + lr;
      const float bb = out_b[n];
      #pragma unroll
      for (int r = 0; r < 4; ++r) {
        const int m = m0 + wr + mf * 16 + lg * 4 + r;
        out[(size_t)m * D_ + n] = acc[mf][nf][r] + bb + x[(size_t)m * D_ + n];
      }
    }
  }
}

// ---------------------------------------------------------------------------
extern "C" void kernel_launch(void* const* d_in, const int* in_sizes, int n_in,
                              void* d_out, int out_size, void* d_ws, size_t ws_size,
                              hipStream_t stream) {
  const float* x     = (const float*)d_in[0];
  const float* emb   = (const float*)d_in[1];
  const float* W1    = (const float*)d_in[2];
  const float* b1    = (const float*)d_in[3];
  const float* W2    = (const float*)d_in[4];
  const float* b2    = (const float*)d_in[5];
  const float* ln_w  = (const float*)d_in[6];
  const float* ln_b  = (const float*)d_in[7];
  const float* emb_W = (const float*)d_in[8];
  const float* emb_b = (const float*)d_in[9];
  const float* out_W = (const float*)d_in[10];
  const float* out_b = (const float*)d_in[11];
  float* out = (float*)d_out;

  float*          emb_out = (float*)((char*)d_ws + WS_EMB_OFF);
  unsigned short* img1    = (unsigned short*)((char*)d_ws + WS_IMG1_OFF);
  unsigned short* img2    = (unsigned short*)((char*)d_ws + WS_IMG2_OFF);
  unsigned short* imgO    = (unsigned short*)((char*)d_ws + WS_IMGO_OFF);
  unsigned short* ybuf    = (unsigned short*)((char*)d_ws + WS_Y_OFF);

  hipMemsetAsync(emb_out, 0, B_ * TWO_D_ * sizeof(float), stream);
  kinit<<<256, 256, 0, stream>>>(W1, W2, out_W, emb, emb_W, emb_b,
                                 img1, img2, imgO, emb_out);
  k1_mfma<<<dim3(NTOK_ / 128, H_), 256, 0, stream>>>(x, img1, img2, b1, b2, ybuf);
  k3f<<<256, 512, 0, stream>>>(ybuf, imgO, out_b, x, ln_w, ln_b, emb_out, out);
}

// Round 14
// 161.403 us; speedup vs baseline: 1.4438x; 1.4438x over previous
//
#include <hip/hip_runtime.h>
#include <hip/hip_bf16.h>
#include <math.h>

// Problem constants
#define B_     4
#define T_     4096
#define H_     8
#define LD_    128
#define FFN_   512
#define D_     1024
#define TED_   2048
#define TWO_D_ 2048
#define NTOK_  (B_ * T_)      // 16384
#define LN_EPS_ 1e-5f

// ws layout (bytes)
#define WS_EMB_OFF   0                         // 32 KB   (B x 2D fp32)
#define WS_IMG1_OFF  (64 * 1024)               // 1 MB  bf16 fragment-ordered W1^T
#define WS_IMG2_OFF  ((64 << 10) + (1 << 20))  // 1 MB  bf16 fragment-ordered W2^T
#define WS_IMGO_OFF  ((64 << 10) + (2 << 20))  // 2 MB  bf16 [n=1024][k=1024]
#define WS_Y_OFF     (8 << 20)                 // 32 MB bf16 y (in-place -> h)

typedef short bf16x8 __attribute__((ext_vector_type(8)));
typedef float f32x4  __attribute__((ext_vector_type(4)));
typedef float f32x16 __attribute__((ext_vector_type(16)));
typedef unsigned int u32x4 __attribute__((ext_vector_type(4)));

// fast SiLU: v * rcp(1 + exp(-v))
__device__ __forceinline__ float siluf(float v) {
  return v * __builtin_amdgcn_rcpf(1.0f + __expf(-v));
}
// fast exact-GELU via Abramowitz-Stegun 7.1.26 erf (|eps| <= 1.5e-7)
__device__ __forceinline__ float geluf(float v) {
  const float s  = v * 0.70710678118654752440f;
  const float ax = fabsf(s);
  const float t  = __builtin_amdgcn_rcpf(fmaf(0.3275911f, ax, 1.0f));
  const float e  = __expf(-ax * ax);
  float p = fmaf(1.061405429f, t, -1.453152027f);
  p = fmaf(p, t, 1.421413741f);
  p = fmaf(p, t, -0.284496736f);
  p = fmaf(p, t, 0.254829592f);
  p = p * t;
  const float erf_ax = fmaf(-p, e, 1.0f);
  const float erf_s  = copysignf(erf_ax, s);
  return 0.5f * v * (1.0f + erf_s);
}
// HW packed f32x2 -> bf16x2 (RNE), single VALU op (T12 recipe; no builtin).
__device__ __forceinline__ unsigned int pack2(float a, float b) {
  unsigned int r;
  asm("v_cvt_pk_bf16_f32 %0, %1, %2" : "=v"(r) : "v"(a), "v"(b));
  return r;
}
__device__ __forceinline__ void unpack8(uint4 u, float* v) {
  v[0] = __uint_as_float(u.x << 16); v[1] = __uint_as_float(u.x & 0xffff0000u);
  v[2] = __uint_as_float(u.y << 16); v[3] = __uint_as_float(u.y & 0xffff0000u);
  v[4] = __uint_as_float(u.z << 16); v[5] = __uint_as_float(u.z & 0xffff0000u);
  v[6] = __uint_as_float(u.w << 16); v[7] = __uint_as_float(u.w & 0xffff0000u);
}

// async global->LDS, 16B/lane; LDS dest is wave-uniform base + lane*16.
__device__ __forceinline__ void gload_lds16(const void* g, void* l) {
#pragma clang diagnostic push
#pragma clang diagnostic ignored "-Waddress-space-conversion"
  __builtin_amdgcn_global_load_lds(
      (const __attribute__((address_space(1))) unsigned int*)g,
      (__attribute__((address_space(3))) unsigned int*)l, 16, 0, 0);
#pragma clang diagnostic pop
}

// ---------------------------------------------------------------------------
// kinit: fused weight-prep + emb projection (one launch, 256 blocks x 256thr).
// ---------------------------------------------------------------------------
__global__ __launch_bounds__(256) void kinit(
    const float* __restrict__ W1, const float* __restrict__ W2,
    const float* __restrict__ out_W,
    const float* __restrict__ emb, const float* __restrict__ emb_W,
    const float* __restrict__ emb_b,
    unsigned short* __restrict__ img1, unsigned short* __restrict__ img2,
    unsigned short* __restrict__ imgO, float* __restrict__ emb_out) {
  const int t = blockIdx.x;
  const int tid = threadIdx.x;
  if (t < 64) {
    const bool is1 = (t < 32);
    const int h = (t & 31) >> 2, q = t & 3;
    const int l = tid & 63, fg = tid >> 6;
    const int l31 = l & 31, hi8 = (l >> 5) * 8;
    #pragma unroll
    for (int i = 0; i < 8; ++i) {
      const int fid = fg * 8 + i;           // 0..31 within quarter
      float val[8];
      size_t dsto;
      if (is1) {
        const int c = q * 4 + (fid >> 3), kb = fid & 7;
        const float* sp = W1 + (size_t)h * 65536 +
                          (size_t)(kb * 16 + hi8) * 512 + c * 32 + l31;
        #pragma unroll
        for (int j = 0; j < 8; ++j) val[j] = sp[(size_t)j * 512];
        dsto = (size_t)h * 65536 + (size_t)(c * 8 + kb) * 512 + l * 8;
      } else {
        const int c = q * 4 + (fid >> 3), kb2 = (fid >> 2) & 1, nt = fid & 3;
        const float* sp = W2 + (size_t)h * 65536 +
                          (size_t)(c * 32 + kb2 * 16 + hi8) * 128 + nt * 32 + l31;
        #pragma unroll
        for (int j = 0; j < 8; ++j) val[j] = sp[(size_t)j * 128];
        dsto = (size_t)h * 65536 + (size_t)(c * 8 + kb2 * 4 + nt) * 512 + l * 8;
      }
      unsigned int p[4];
      #pragma unroll
      for (int qq = 0; qq < 4; ++qq) p[qq] = pack2(val[2 * qq], val[2 * qq + 1]);
      *reinterpret_cast<uint4*>((is1 ? img1 : img2) + dsto) =
          make_uint4(p[0], p[1], p[2], p[3]);
    }
    return;
  }
  if (t < 128) {
    __shared__ float ls[128][129];
    const int tt = t - 64, tr = tt >> 3, tc = tt & 7;
    const float* src = out_W + (size_t)tr * 128 * 1024 + tc * 128;
    unsigned short* dst = imgO + (size_t)tc * 128 * 1024 + tr * 128;
    for (int i = tid; i < 128 * 32; i += 256) {
      const int r = i >> 5, c4 = (i & 31) << 2;
      const float4 v = *reinterpret_cast<const float4*>(src + (size_t)r * 1024 + c4);
      ls[r][c4] = v.x; ls[r][c4 + 1] = v.y; ls[r][c4 + 2] = v.z; ls[r][c4 + 3] = v.w;
    }
    __syncthreads();
    for (int u = tid; u < 2048; u += 256) {
      const int nn = u >> 4, kb = (u & 15) << 3;
      unsigned int p[4];
      #pragma unroll
      for (int qq = 0; qq < 4; ++qq)
        p[qq] = pack2(ls[kb + 2 * qq][nn], ls[kb + 2 * qq + 1][nn]);
      *reinterpret_cast<uint4*>(dst + (size_t)nn * 1024 + kb) =
          make_uint4(p[0], p[1], p[2], p[3]);
    }
    return;
  }
  {
    __shared__ float se[B_][128];
    const int bid = t - 128;
    const int j   = (bid & 7) * 256 + tid;
    const int k0  = (bid >> 3) * 128;
    for (int i = tid; i < B_ * 128; i += 256) {
      const int b = i >> 7, k = i & 127;
      se[b][k] = siluf(emb[b * TED_ + k0 + k]);
    }
    __syncthreads();
    float a0 = 0.f, a1 = 0.f, a2 = 0.f, a3 = 0.f;
    const float* Wp = emb_W + (size_t)k0 * TWO_D_ + j;
    for (int k = 0; k < 128; ++k) {
      const float w = Wp[(size_t)k * TWO_D_];
      a0 += se[0][k] * w; a1 += se[1][k] * w;
      a2 += se[2][k] * w; a3 += se[3][k] * w;
    }
    if ((bid >> 3) == 0) {
      const float bb = emb_b[j];
      a0 += bb; a1 += bb; a2 += bb; a3 += bb;
    }
    atomicAdd(&emb_out[0 * TWO_D_ + j], a0);
    atomicAdd(&emb_out[1 * TWO_D_ + j], a1);
    atomicAdd(&emb_out[2 * TWO_D_ + j], a2);
    atomicAdd(&emb_out[3 * TWO_D_ + j], a3);
  }
}

// ---------------------------------------------------------------------------
// k1 (r9 best-known: ~93 us, 0 bank conflicts): per-head MLP, 4 waves x 32
// tokens, 2-phase dbuf LDS weight staging, cvt_pk packing, setprio.
// ---------------------------------------------------------------------------
__global__ __launch_bounds__(256, 3) void k1_mfma(
    const float* __restrict__ x,
    const unsigned short* __restrict__ img1,
    const unsigned short* __restrict__ img2,
    const float* __restrict__ b1, const float* __restrict__ b2,
    unsigned short* __restrict__ y) {
  __shared__ unsigned short wbuf[2][16 * 512];  // 2 x 16 KB
  const int h = blockIdx.y;
  const int tid = threadIdx.x, w = tid >> 6, l = tid & 63;
  const int t0 = blockIdx.x * 128 + w * 32;
  const int l31 = l & 31, hi = l >> 5;

  const unsigned short* s1 = img1 + ((size_t)h << 16);
  const unsigned short* s2 = img2 + ((size_t)h << 16);

  auto stage = [&](unsigned short* buf, int c) {
    #pragma unroll
    for (int i = 0; i < 4; ++i) {
      const int slot = w * 4 + i;                     // wave-uniform
      const unsigned short* src = (slot < 8)
          ? (s1 + (size_t)(c * 8 + slot) * 512 + l * 8)
          : (s2 + (size_t)(c * 8 + (slot - 8)) * 512 + l * 8);
      gload_lds16(src, buf + slot * 512);
    }
  };

  bf16x8 xf[8];
  {
    const float* xr = x + (size_t)(t0 + l31) * D_ + h * LD_ + hi * 8;
    #pragma unroll
    for (int kb = 0; kb < 8; ++kb) {
      const float4 a = *reinterpret_cast<const float4*>(xr + kb * 16);
      const float4 b = *reinterpret_cast<const float4*>(xr + kb * 16 + 4);
      u32x4 u;
      u[0] = pack2(a.x, a.y); u[1] = pack2(a.z, a.w);
      u[2] = pack2(b.x, b.y); u[3] = pack2(b.z, b.w);
      xf[kb] = __builtin_bit_cast(bf16x8, u);
    }
  }

  f32x16 acc2[4];
  #pragma unroll
  for (int nt = 0; nt < 4; ++nt)
    #pragma unroll
    for (int r = 0; r < 16; ++r) acc2[nt][r] = 0.f;

  auto compute = [&](const unsigned short* buf, int c) {
    f32x16 acc1;
    #pragma unroll
    for (int r = 0; r < 16; ++r) acc1[r] = 0.f;
    __builtin_amdgcn_s_setprio(1);
    #pragma unroll
    for (int kb = 0; kb < 8; ++kb) {
      const bf16x8 a = *reinterpret_cast<const bf16x8*>(buf + kb * 512 + l * 8);
      acc1 = __builtin_amdgcn_mfma_f32_32x32x16_bf16(a, xf[kb], acc1, 0, 0, 0);
    }
    __builtin_amdgcn_s_setprio(0);
    float g[16];
    #pragma unroll
    for (int q = 0; q < 4; ++q) {
      const float4 bq = *reinterpret_cast<const float4*>(
          b1 + h * FFN_ + c * 32 + q * 8 + hi * 4);
      g[q*4+0] = geluf(acc1[q*4+0] + bq.x);
      g[q*4+1] = geluf(acc1[q*4+1] + bq.y);
      g[q*4+2] = geluf(acc1[q*4+2] + bq.z);
      g[q*4+3] = geluf(acc1[q*4+3] + bq.w);
    }
    unsigned int P[4][2];
    #pragma unroll
    for (int q = 0; q < 4; ++q) {
      P[q][0] = pack2(g[q*4+0], g[q*4+1]);
      P[q][1] = pack2(g[q*4+2], g[q*4+3]);
    }
    unsigned int A2[2][4];
    #pragma unroll
    for (int half = 0; half < 2; ++half) {
      const int qe = half * 2, qo = half * 2 + 1;
      #pragma unroll
      for (int s = 0; s < 2; ++s) {
        const unsigned int offer = hi ? P[qe][s] : P[qo][s];
        const unsigned int recv =
            (unsigned int)__shfl_xor((int)offer, 32);
        A2[half][s]     = hi ? recv : P[qe][s];
        A2[half][s + 2] = hi ? P[qo][s] : recv;
      }
    }
    __builtin_amdgcn_s_setprio(1);
    #pragma unroll
    for (int kb2 = 0; kb2 < 2; ++kb2) {
      u32x4 t;
      t[0] = A2[kb2][0]; t[1] = A2[kb2][1];
      t[2] = A2[kb2][2]; t[3] = A2[kb2][3];
      const bf16x8 a2 = __builtin_bit_cast(bf16x8, t);
      #pragma unroll
      for (int nt = 0; nt < 4; ++nt) {
        const bf16x8 b2f = *reinterpret_cast<const bf16x8*>(
            buf + (8 + kb2 * 4 + nt) * 512 + l * 8);
        acc2[nt] = __builtin_amdgcn_mfma_f32_32x32x16_bf16(a2, b2f, acc2[nt], 0, 0, 0);
      }
    }
    __builtin_amdgcn_s_setprio(0);
  };

  stage(wbuf[0], 0);
  __syncthreads();
  #pragma unroll 1
  for (int c = 0; c < 16; c += 2) {
    if (c + 1 < 16) stage(wbuf[1], c + 1);
    compute(wbuf[0], c);
    __syncthreads();
    if (c + 2 < 16) stage(wbuf[0], c + 2);
    compute(wbuf[1], c + 1);
    __syncthreads();
  }

  #pragma unroll
  for (int nt = 0; nt < 4; ++nt) {
    const int d = nt * 32 + l31;
    const float bb = b2[h * LD_ + d];
    #pragma unroll
    for (int rp = 0; rp < 8; ++rp) {
      const int r0 = 2 * rp, r1 = 2 * rp + 1;
      const unsigned int pk = pack2(acc2[nt][r0] + bb, acc2[nt][r1] + bb);
      const int tA = t0 + (r0 & 3) + 8 * (r0 >> 2) + 4 * hi;
      const int tB = tA + 1;
      y[(size_t)tA * D_ + h * LD_ + d] = (unsigned short)(pk & 0xffffu);
      y[(size_t)tB * D_ + h * LD_ + d] = (unsigned short)(pk >> 16);
    }
  }
}

// ---------------------------------------------------------------------------
// k2: LN + modulate + SiLU. One wave per token; in-place bf16 -> bf16.
// ---------------------------------------------------------------------------
__global__ __launch_bounds__(256) void k2_ln(
    unsigned short* __restrict__ y, const float* __restrict__ ln_w,
    const float* __restrict__ ln_b, const float* __restrict__ emb_out) {
  const int tid = threadIdx.x;
  const int bt  = blockIdx.x * 4 + (tid >> 6);
  const int l   = tid & 63;
  const int b   = bt >> 12;
  unsigned short* rowp = y + (size_t)bt * D_ + l * 16;
  const uint4 u0 = *reinterpret_cast<const uint4*>(rowp);
  const uint4 u1 = *reinterpret_cast<const uint4*>(rowp + 8);
  float v[16];
  unpack8(u0, v); unpack8(u1, v + 8);
  float s = 0.f, s2 = 0.f;
  #pragma unroll
  for (int j = 0; j < 16; ++j) { s += v[j]; s2 += v[j] * v[j]; }
  #pragma unroll
  for (int off = 1; off < 64; off <<= 1) {
    s  += __shfl_xor(s, off);
    s2 += __shfl_xor(s2, off);
  }
  const float mu   = s * (1.0f / D_);
  const float rstd = rsqrtf(s2 * (1.0f / D_) - mu * mu + LN_EPS_);
  const int d0 = l * 16;
  float r[16];
  #pragma unroll
  for (int q = 0; q < 4; ++q) {
    const float4 lw = *reinterpret_cast<const float4*>(ln_w + d0 + q * 4);
    const float4 lb = *reinterpret_cast<const float4*>(ln_b + d0 + q * 4);
    const float4 sc = *reinterpret_cast<const float4*>(emb_out + (size_t)b * TWO_D_ + d0 + q * 4);
    const float4 sh = *reinterpret_cast<const float4*>(emb_out + (size_t)b * TWO_D_ + D_ + d0 + q * 4);
    r[q*4+0] = siluf(((v[q*4+0] - mu) * rstd * lw.x + lb.x) * (1.f + sc.x) + sh.x);
    r[q*4+1] = siluf(((v[q*4+1] - mu) * rstd * lw.y + lb.y) * (1.f + sc.y) + sh.y);
    r[q*4+2] = siluf(((v[q*4+2] - mu) * rstd * lw.z + lb.z) * (1.f + sc.z) + sh.z);
    r[q*4+3] = siluf(((v[q*4+3] - mu) * rstd * lw.w + lb.w) * (1.f + sc.w) + sh.w);
  }
  uint4 o0, o1;
  o0.x = pack2(r[0], r[1]);  o0.y = pack2(r[2], r[3]);
  o0.z = pack2(r[4], r[5]);  o0.w = pack2(r[6], r[7]);
  o1.x = pack2(r[8], r[9]);  o1.y = pack2(r[10], r[11]);
  o1.z = pack2(r[12], r[13]); o1.w = pack2(r[14], r[15]);
  *reinterpret_cast<uint4*>(rowp)     = o0;
  *reinterpret_cast<uint4*>(rowp + 8) = o1;
}

// ---------------------------------------------------------------------------
// k3: out = x + (h @ out_W + out_b). 256x256 tile, BK=64, 8 waves (2Mx4N),
// 2-phase schedule, T2 swizzle with rule-21 pairing. (r11, at HBM roofline.)
// ---------------------------------------------------------------------------
__global__ __launch_bounds__(512) void k3_mfma(
    const unsigned short* __restrict__ hb,
    const unsigned short* __restrict__ imgO,
    const float* __restrict__ out_b, const float* __restrict__ x,
    float* __restrict__ out) {
  __shared__ unsigned short As[2][256 * 64];   // 2 x 32 KB, swizzled content
  __shared__ unsigned short Bs[2][256 * 64];   // 2 x 32 KB
  const int bid = blockIdx.x;
  const int swz = (bid & 7) * 32 + (bid >> 3);   // XCD-bijective (256 % 8 == 0)
  const int m0 = (swz >> 2) * 256;               // 64 m-blocks
  const int n0 = (swz & 3) * 256;                // 4 n-blocks
  const int tid = threadIdx.x, w = tid >> 6, l = tid & 63;
  const int lr = l & 15, lg = l >> 4;
  const int wr = (w >> 2) * 128;                 // wave row base (2 M-groups)
  const int wc = (w & 3) * 64;                   // wave col base (4 N-groups)

  f32x4 acc[8][4];
  #pragma unroll
  for (int mf = 0; mf < 8; ++mf)
    #pragma unroll
    for (int nf = 0; nf < 4; ++nf)
      acc[mf][nf] = (f32x4){0.f, 0.f, 0.f, 0.f};

  const int grl  = l >> 3;                            // 0..7: row within slab
  const int gcol = (((l & 7) ^ ((l >> 3) & 7)) * 8);  // swizzled col (elems)

  auto stage = [&](int kt, int b) {
    #pragma unroll
    for (int j = 0; j < 4; ++j) {
      const int slab = j * 8 + w;                 // wave-uniform
      const int row = slab * 8 + grl;             // 0..255
      gload_lds16(hb   + (size_t)(m0 + row) * D_ + kt * 64 + gcol,
                  &As[b][slab * 512]);
      gload_lds16(imgO + (size_t)(n0 + row) * D_ + kt * 64 + gcol,
                  &Bs[b][slab * 512]);
    }
  };

  auto compute = [&](int b) {
    #pragma unroll
    for (int ks = 0; ks < 2; ++ks) {
      bf16x8 af[8], bf[4];
      #pragma unroll
      for (int mf = 0; mf < 8; ++mf) {
        const int row = wr + mf * 16 + lr;
        const int u = (ks * 4 + lg) ^ (row & 7);
        af[mf] = *reinterpret_cast<const bf16x8*>(&As[b][row * 64 + u * 8]);
      }
      #pragma unroll
      for (int nf = 0; nf < 4; ++nf) {
        const int row = wc + nf * 16 + lr;
        const int u = (ks * 4 + lg) ^ (row & 7);
        bf[nf] = *reinterpret_cast<const bf16x8*>(&Bs[b][row * 64 + u * 8]);
      }
      #pragma unroll
      for (int mf = 0; mf < 8; ++mf)
        #pragma unroll
        for (int nf = 0; nf < 4; ++nf)
          acc[mf][nf] = __builtin_amdgcn_mfma_f32_16x16x32_bf16(
              af[mf], bf[nf], acc[mf][nf], 0, 0, 0);
    }
  };

  stage(0, 0);
  __syncthreads();
  #pragma unroll 1
  for (int kt = 0; kt < 16; ++kt) {
    const int cur = kt & 1;
    if (kt + 1 < 16) stage(kt + 1, cur ^ 1);  // hides under 64 MFMA
    compute(cur);
    __syncthreads();
  }

  #pragma unroll
  for (int mf = 0; mf < 8; ++mf) {
    #pragma unroll
    for (int nf = 0; nf < 4; ++nf) {
      const int n = n0 + wc + nf * 16 + lr;
      const float bb = out_b[n];
      #pragma unroll
      for (int r = 0; r < 4; ++r) {
        const int m = m0 + wr + mf * 16 + lg * 4 + r;
        out[(size_t)m * D_ + n] = acc[mf][nf][r] + bb + x[(size_t)m * D_ + n];
      }
    }
  }
}

// ---------------------------------------------------------------------------
extern "C" void kernel_launch(void* const* d_in, const int* in_sizes, int n_in,
                              void* d_out, int out_size, void* d_ws, size_t ws_size,
                              hipStream_t stream) {
  const float* x     = (const float*)d_in[0];
  const float* emb   = (const float*)d_in[1];
  const float* W1    = (const float*)d_in[2];
  const float* b1    = (const float*)d_in[3];
  const float* W2    = (const float*)d_in[4];
  const float* b2    = (const float*)d_in[5];
  const float* ln_w  = (const float*)d_in[6];
  const float* ln_b  = (const float*)d_in[7];
  const float* emb_W = (const float*)d_in[8];
  const float* emb_b = (const float*)d_in[9];
  const float* out_W = (const float*)d_in[10];
  const float* out_b = (const float*)d_in[11];
  float* out = (float*)d_out;

  float*          emb_out = (float*)((char*)d_ws + WS_EMB_OFF);
  unsigned short* img1    = (unsigned short*)((char*)d_ws + WS_IMG1_OFF);
  unsigned short* img2    = (unsigned short*)((char*)d_ws + WS_IMG2_OFF);
  unsigned short* imgO    = (unsigned short*)((char*)d_ws + WS_IMGO_OFF);
  unsigned short* ybuf    = (unsigned short*)((char*)d_ws + WS_Y_OFF);

  hipMemsetAsync(emb_out, 0, B_ * TWO_D_ * sizeof(float), stream);
  kinit<<<256, 256, 0, stream>>>(W1, W2, out_W, emb, emb_W, emb_b,
                                 img1, img2, imgO, emb_out);
  k1_mfma<<<dim3(NTOK_ / 128, H_), 256, 0, stream>>>(x, img1, img2, b1, b2, ybuf);
  k2_ln<<<NTOK_ / 4, 256, 0, stream>>>(ybuf, ln_w, ln_b, emb_out);
  k3_mfma<<<256, 512, 0, stream>>>(ybuf, imgO, out_b, x, out);
}